// Round 10
// baseline (971.829 us; speedup 1.0000x reference)
//
#include <hip/hip_runtime.h>
#include <math.h>

#define N_NODES 50000
#define N_EDGES 1600000
#define HID 128
#define NF 128
#define NG 50
#define NL 6
#define NSEG 64
#define TAB2 4096
#define CUTOFF 20.0f
#define LOG2F_ 0.6931471805599453f
#define SENTINEL 0x0FFF0000u   // j=4095 (W*C=0 row), s=0

typedef unsigned short u16;
typedef unsigned long long u64;
typedef __attribute__((ext_vector_type(8))) short short8;            // 8 bf16 MFMA A/B frag
typedef __attribute__((ext_vector_type(8))) unsigned short ushort8;  // 16B bf16 load
typedef __attribute__((ext_vector_type(4))) float f32x4;             // MFMA C/D frag

__device__ __forceinline__ float ssp(float x){
  float sp = fmaxf(x, 0.f) + log1pf(expf(-fabsf(x)));
  return sp - LOG2F_;
}
__device__ __forceinline__ float b2f(u16 u){
  unsigned v = ((unsigned)u) << 16; float f; __builtin_memcpy(&f, &v, 4); return f;
}
__device__ __forceinline__ u16 f2b(float f){
  unsigned u; __builtin_memcpy(&u, &f, 4);
  u += 0x7FFFu + ((u >> 16) & 1u);
  return (u16)(u >> 16);
}
__device__ __forceinline__ float u2f(unsigned u){
  float f; __builtin_memcpy(&f, &u, 4); return f;
}
// packed pair of bf16 (in a u32) FMA into two f32 accumulators
__device__ __forceinline__ void fma2(unsigned hp, unsigned wp, float& a0, float& a1){
  a0 = fmaf(u2f(hp << 16), u2f(wp << 16), a0);
  a1 = fmaf(u2f(hp & 0xFFFF0000u), u2f(wp & 0xFFFF0000u), a1);
}
// XOR-swizzled byte offset within a [16][128] bf16 tile (256B rows).
__device__ __forceinline__ int swz(int row, int colb){
  return row*256 + (colb ^ ((row & 15) << 4));
}

// ---------------- degree histogram (dst half only, int4) ----------------
__global__ __launch_bounds__(256) void k_hist(const int* __restrict__ ei_dst,
                                              int* __restrict__ deg){
  int e4 = blockIdx.x*blockDim.x + threadIdx.x;
  if (e4 < N_EDGES/4){
    int4 d = ((const int4*)ei_dst)[e4];
    atomicAdd(&deg[d.x], 1);
    atomicAdd(&deg[d.y], 1);
    atomicAdd(&deg[d.z], 1);
    atomicAdd(&deg[d.w], 1);
  }
}

// ---------------- parallel scan over EVEN-PADDED degrees: phase 1 ----------------
__global__ __launch_bounds__(1024) void k_scan1(const int* __restrict__ deg,
                                                int* __restrict__ row_start,
                                                int* __restrict__ bsum){
  int i = blockIdx.x*1024 + threadIdx.x;
  int lane = threadIdx.x & 63, w = threadIdx.x >> 6;
  int x = (i < N_NODES) ? ((deg[i] + 1) & ~1) : 0;   // pad to even
  int v = x;
  #pragma unroll
  for (int off = 1; off < 64; off <<= 1){
    int t = __shfl_up(v, off);
    if (lane >= off) v += t;
  }
  __shared__ int ws[16];
  if (lane == 63) ws[w] = v;
  __syncthreads();
  if (w == 0 && lane < 16){
    int t = ws[lane];
    #pragma unroll
    for (int off = 1; off < 16; off <<= 1){
      int u = __shfl_up(t, off);
      if (lane >= off) t += u;
    }
    ws[lane] = t;
  }
  __syncthreads();
  int woff = (w > 0) ? ws[w-1] : 0;
  if (i < N_NODES) row_start[i] = woff + v - x;  // block-local exclusive
  if (threadIdx.x == 1023) bsum[blockIdx.x] = woff + v;
}

// ---------------- parallel scan: phase 2 (add block offsets) ----------------
__global__ __launch_bounds__(1024) void k_scan2(const int* __restrict__ bsum,
                                                const int* __restrict__ deg,
                                                int* __restrict__ row_start){
  __shared__ int boff_s;
  if (threadIdx.x < 64){
    int lane = threadIdx.x;
    int acc = 0;
    for (int b = lane; b < blockIdx.x; b += 64) acc += bsum[b];
    #pragma unroll
    for (int off = 32; off >= 1; off >>= 1) acc += __shfl_xor(acc, off);
    if (lane == 0) boff_s = acc;
  }
  __syncthreads();
  int i = blockIdx.x*1024 + threadIdx.x;
  if (i < N_NODES){
    int r = row_start[i] + boff_s;
    row_start[i] = r;
    if (i == N_NODES - 1) row_start[N_NODES] = r + ((deg[i] + 1) & ~1);
  }
}

// ---------------- sentinel fill for odd-degree pad slots ----------------
__global__ __launch_bounds__(256) void k_pad(const int* __restrict__ deg,
                                             const int* __restrict__ row_start,
                                             unsigned* __restrict__ csr_pack){
  int i = blockIdx.x*blockDim.x + threadIdx.x;
  if (i < N_NODES && (deg[i] & 1))
    csr_pack[row_start[i] + deg[i]] = SENTINEL;
}

// fused: distance + table index + pack + scatter (nt store)
__global__ __launch_bounds__(256) void k_scatter(const int* __restrict__ ei,
                                                 const float* __restrict__ pos,
                                                 const int* __restrict__ row_start,
                                                 int* __restrict__ cursor,
                                                 unsigned* __restrict__ csr_pack){
  const float INV_STEP = (TAB2 - 1) / CUTOFF;
  for (int e = blockIdx.x*blockDim.x + threadIdx.x; e < N_EDGES; e += gridDim.x*blockDim.x){
    int s = ei[e], t = ei[N_EDGES + e];
    float dx = pos[3*s]   - pos[3*t];
    float dy = pos[3*s+1] - pos[3*t+1];
    float dz = pos[3*s+2] - pos[3*t+2];
    float d = sqrtf(dx*dx + dy*dy + dz*dz);
    int j = (int)(d * INV_STEP + 0.5f);
    if (j > TAB2 - 1) j = TAB2 - 1;
    int slot = atomicAdd(&cursor[t], 1);
    int p = row_start[t] + slot;
    __builtin_nontemporal_store(((unsigned)j << 16) | (unsigned)s, &csr_pack[p]);
  }
}

// ---------------- filter table: W_l(d)*C(d), bf16, plain [l][j][f] ----------------
__global__ __launch_bounds__(128) void k_table(const float* __restrict__ w1, const float* __restrict__ b1,
                                               const float* __restrict__ w2, const float* __restrict__ b2,
                                               u16* __restrict__ tab){
  int l = blockIdx.x / TAB2, j = blockIdx.x % TAB2;
  int tid = threadIdx.x;
  float d = j * (CUTOFF / (TAB2 - 1));
  __shared__ float ea[NG];
  __shared__ float sbuf[NF];
  if (tid < NG){
    const float gstep = CUTOFF / (NG - 1);
    const float coeff = -0.5f / (gstep * gstep);
    float u = d - tid * gstep;
    ea[tid] = expf(coeff * u * u);
  }
  __syncthreads();
  float z = b1[l*NF + tid];
  for (int k = 0; k < NG; k++) z += ea[k] * w1[(l*NG + k)*NF + tid];
  sbuf[tid] = ssp(z);
  __syncthreads();
  float W = b2[l*NF + tid];
  for (int k = 0; k < NF; k++) W += sbuf[k] * w2[(l*NF + k)*NF + tid];
  float C = 0.5f * (cosf(d * (float)M_PI / CUTOFF) + 1.f);
  tab[((size_t)l*TAB2 + j)*NF + tid] = f2b(W * C);
}

// ---------------- weight convert: [in][out] fp32 -> [out][in] bf16 (128x128) ----------------
__global__ __launch_bounds__(128) void k_wconv(const float* __restrict__ w, u16* __restrict__ wT){
  int m = blockIdx.x >> 7, o = blockIdx.x & 127;
  int i = threadIdx.x;
  wT[((size_t)m*128 + o)*128 + i] = f2b(w[((size_t)m*128 + i)*128 + o]);
}
// [128][64] fp32 -> [64][128] bf16
__global__ __launch_bounds__(128) void k_wconv64(const float* __restrict__ w, u16* __restrict__ wT){
  int o = blockIdx.x;
  int i = threadIdx.x;
  wT[o*128 + i] = f2b(w[i*64 + o]);
}

// ---------------- layer-0 lin1: hxb = bf16(h @ w1) via MFMA ----------------
__global__ __launch_bounds__(256) void k_lin1m(const float* __restrict__ h,
                                               const u16* __restrict__ w1T,
                                               u16* __restrict__ hxb){
  int tid = threadIdx.x;
  int wv = tid >> 6, l = tid & 63;
  int n0 = blockIdx.x * 64 + wv * 16;
  if (n0 >= N_NODES) return;
  int li = l & 15, lh = l >> 4;
  __shared__ u16 tiles[4][16*128];
  char* tb = (char*)&tiles[wv][0];

  short8 a[4];
  #pragma unroll
  for (int kc = 0; kc < 4; kc++){
    const float* p = &h[(size_t)(n0 + li)*HID + kc*32 + lh*8];
    union { short8 v; u16 u[8]; } t;
    #pragma unroll
    for (int e = 0; e < 8; e++) t.u[e] = f2b(p[e]);
    a[kc] = t.v;
  }
  #pragma unroll
  for (int fc = 0; fc < 8; fc++){
    f32x4 acc = {0.f,0.f,0.f,0.f};
    #pragma unroll
    for (int kc = 0; kc < 4; kc++){
      short8 b = *(const short8*)&w1T[(size_t)(fc*16 + li)*HID + kc*32 + lh*8];
      acc = __builtin_amdgcn_mfma_f32_16x16x32_bf16(a[kc], b, acc, 0, 0, 0);
    }
    #pragma unroll
    for (int r = 0; r < 4; r++)
      *(u16*)(tb + swz(lh*4 + r, fc*32 + li*2)) = f2b(acc[r]);
  }
  #pragma unroll
  for (int g = 0; g < 4; g++){
    int row = g*4 + lh;
    short8 v = *(const short8*)(tb + swz(row, li*16));
    *(short8*)&hxb[(size_t)(n0 + row)*NF + li*8] = v;
  }
}

// ---------------- edge aggregation: pipelined, pair-per-group, even-padded CSR ----------------
__global__ __launch_bounds__(256) void k_edgeagg(const int* __restrict__ row_start,
                                                 const unsigned* __restrict__ csr_pack,
                                                 const u16* __restrict__ tab_l,
                                                 const u16* __restrict__ hxb,
                                                 u16* __restrict__ aggb){
  int wave = threadIdx.x >> 6, lane = threadIdx.x & 63;
  int i = blockIdx.x * 4 + wave;
  int li = lane & 15, g = lane >> 4;
  int rs = row_start[i], re = row_start[i + 1];   // even length, rs even
  int len = re - rs;
  float acc0[8], acc1[8];
  #pragma unroll
  for (int r = 0; r < 8; r++){ acc0[r] = 0.f; acc1[r] = 0.f; }

  int p = rs + 2*g;
  int nmain = len >> 3;   // uniform across groups
  u64 v = 0;
  if (p < re) v = __builtin_nontemporal_load((const u64*)&csr_pack[p]);

  for (int t = 0; t < nmain; ++t){
    unsigned v0 = (unsigned)v, v1 = (unsigned)(v >> 32);
    int s0 = (int)(v0 & 0xFFFFu), j0 = (int)(v0 >> 16);
    int s1 = (int)(v1 & 0xFFFFu), j1 = (int)(v1 >> 16);
    uint4 hv0 = *(const uint4*)&hxb[(size_t)s0 * NF + li*8];
    uint4 wv0 = *(const uint4*)&tab_l[(size_t)j0 * NF + li*8];
    uint4 hv1 = *(const uint4*)&hxb[(size_t)s1 * NF + li*8];
    uint4 wv1 = *(const uint4*)&tab_l[(size_t)j1 * NF + li*8];
    // prefetch next pair's packs (csr_pack padded; value unused unless next iter runs)
    u64 vn = __builtin_nontemporal_load((const u64*)&csr_pack[p + 8]);
    fma2(hv0.x, wv0.x, acc0[0], acc0[1]);
    fma2(hv0.y, wv0.y, acc0[2], acc0[3]);
    fma2(hv0.z, wv0.z, acc0[4], acc0[5]);
    fma2(hv0.w, wv0.w, acc0[6], acc0[7]);
    fma2(hv1.x, wv1.x, acc1[0], acc1[1]);
    fma2(hv1.y, wv1.y, acc1[2], acc1[3]);
    fma2(hv1.z, wv1.z, acc1[4], acc1[5]);
    fma2(hv1.w, wv1.w, acc1[6], acc1[7]);
    v = vn; p += 8;
  }
  // tail: at most one pair per group
  if (p < re){
    unsigned v0 = (unsigned)v, v1 = (unsigned)(v >> 32);
    int s0 = (int)(v0 & 0xFFFFu), j0 = (int)(v0 >> 16);
    int s1 = (int)(v1 & 0xFFFFu), j1 = (int)(v1 >> 16);
    uint4 hv0 = *(const uint4*)&hxb[(size_t)s0 * NF + li*8];
    uint4 wv0 = *(const uint4*)&tab_l[(size_t)j0 * NF + li*8];
    uint4 hv1 = *(const uint4*)&hxb[(size_t)s1 * NF + li*8];
    uint4 wv1 = *(const uint4*)&tab_l[(size_t)j1 * NF + li*8];
    fma2(hv0.x, wv0.x, acc0[0], acc0[1]);
    fma2(hv0.y, wv0.y, acc0[2], acc0[3]);
    fma2(hv0.z, wv0.z, acc0[4], acc0[5]);
    fma2(hv0.w, wv0.w, acc0[6], acc0[7]);
    fma2(hv1.x, wv1.x, acc1[0], acc1[1]);
    fma2(hv1.y, wv1.y, acc1[2], acc1[3]);
    fma2(hv1.z, wv1.z, acc1[4], acc1[5]);
    fma2(hv1.w, wv1.w, acc1[6], acc1[7]);
  }
  #pragma unroll
  for (int r = 0; r < 8; r++){
    float a = acc0[r] + acc1[r];
    a += __shfl_xor(a, 16);
    a += __shfl_xor(a, 32);
    acc0[r] = a;
  }
  if (g == 0){
    // acc0[2k], acc0[2k+1] are features li*8 + {2k, 2k+1}
    union { short8 v; u16 u[8]; } o;
    #pragma unroll
    for (int r = 0; r < 8; r++) o.u[r] = f2b(acc0[r]);
    *(short8*)&aggb[(size_t)i * NF + li*8] = o.v;
  }
}

// ---------------- fused node update via MFMA ----------------
__global__ __launch_bounds__(256) void k_nodefuse(const u16* __restrict__ aggb,
                                                  const u16* __restrict__ w2T, const float* __restrict__ b2b,
                                                  const u16* __restrict__ lT,  const float* __restrict__ linb,
                                                  float* __restrict__ h,
                                                  const u16* __restrict__ w1nT,
                                                  u16* __restrict__ hxb){
  int tid = threadIdx.x;
  int wv = tid >> 6, l = tid & 63;
  int n0 = blockIdx.x * 64 + wv * 16;
  if (n0 >= N_NODES) return;
  int li = l & 15, lh = l >> 4;
  __shared__ u16 tiles[4][16*128];
  char* tb = (char*)&tiles[wv][0];

  short8 a[4];
  #pragma unroll
  for (int kc = 0; kc < 4; kc++)
    a[kc] = *(const short8*)&aggb[(size_t)(n0 + li)*NF + kc*32 + lh*8];

  #pragma unroll
  for (int fc = 0; fc < 8; fc++){
    f32x4 acc = {0.f,0.f,0.f,0.f};
    #pragma unroll
    for (int kc = 0; kc < 4; kc++){
      short8 b = *(const short8*)&w2T[(size_t)(fc*16 + li)*NF + kc*32 + lh*8];
      acc = __builtin_amdgcn_mfma_f32_16x16x32_bf16(a[kc], b, acc, 0, 0, 0);
    }
    float bias = b2b[fc*16 + li];
    #pragma unroll
    for (int r = 0; r < 4; r++){
      float s = ssp(acc[r] + bias);
      *(u16*)(tb + swz(lh*4 + r, fc*32 + li*2)) = f2b(s);
    }
  }

  short8 a2[4];
  #pragma unroll
  for (int kc = 0; kc < 4; kc++)
    a2[kc] = *(const short8*)(tb + swz(li, kc*64 + lh*16));

  #pragma unroll
  for (int fc = 0; fc < 8; fc++){
    f32x4 acc = {0.f,0.f,0.f,0.f};
    #pragma unroll
    for (int kc = 0; kc < 4; kc++){
      short8 b = *(const short8*)&lT[(size_t)(fc*16 + li)*HID + kc*32 + lh*8];
      acc = __builtin_amdgcn_mfma_f32_16x16x32_bf16(a2[kc], b, acc, 0, 0, 0);
    }
    float bias = linb[fc*16 + li];
    #pragma unroll
    for (int r = 0; r < 4; r++){
      int i = lh*4 + r;
      size_t off = (size_t)(n0 + i)*HID + fc*16 + li;
      float hn = h[off] + acc[r] + bias;
      h[off] = hn;
      if (w1nT) *(u16*)(tb + swz(i, fc*32 + li*2)) = f2b(hn);
    }
  }
  if (!w1nT) return;

  short8 a3[4];
  #pragma unroll
  for (int kc = 0; kc < 4; kc++)
    a3[kc] = *(const short8*)(tb + swz(li, kc*64 + lh*16));
  #pragma unroll
  for (int fc = 0; fc < 8; fc++){
    f32x4 acc = {0.f,0.f,0.f,0.f};
    #pragma unroll
    for (int kc = 0; kc < 4; kc++){
      short8 b = *(const short8*)&w1nT[(size_t)(fc*16 + li)*HID + kc*32 + lh*8];
      acc = __builtin_amdgcn_mfma_f32_16x16x32_bf16(a3[kc], b, acc, 0, 0, 0);
    }
    #pragma unroll
    for (int r = 0; r < 4; r++)
      *(u16*)(tb + swz(lh*4 + r, fc*32 + li*2)) = f2b(acc[r]);
  }
  #pragma unroll
  for (int g = 0; g < 4; g++){
    int row = g*4 + lh;
    short8 v = *(const short8*)(tb + swz(row, li*16));
    *(short8*)&hxb[(size_t)(n0 + row)*NF + li*8] = v;
  }
}

// ---------------- readout via MFMA + wave segmented scan ----------------
__global__ __launch_bounds__(256) void k_out(const float* __restrict__ h,
                                             const u16* __restrict__ o1wT, const float* __restrict__ b1,
                                             const float* __restrict__ w2, const float* __restrict__ b2,
                                             const int* __restrict__ batch, float* __restrict__ out){
  int tid = threadIdx.x;
  int wv = tid >> 6, l = tid & 63;
  int base = blockIdx.x * 64 + wv * 16;
  if (base >= N_NODES) return;
  int li = l & 15, lh = l >> 4;
  __shared__ float o_s[4][16];

  short8 a[4];
  #pragma unroll
  for (int kc = 0; kc < 4; kc++){
    const float* p = &h[(size_t)(base + li)*HID + kc*32 + lh*8];
    union { short8 v; u16 u[8]; } t;
    #pragma unroll
    for (int e = 0; e < 8; e++) t.u[e] = f2b(p[e]);
    a[kc] = t.v;
  }
  float psum[4] = {0.f,0.f,0.f,0.f};
  #pragma unroll
  for (int fc = 0; fc < 4; fc++){
    f32x4 acc = {0.f,0.f,0.f,0.f};
    #pragma unroll
    for (int kc = 0; kc < 4; kc++){
      short8 b = *(const short8*)&o1wT[(size_t)(fc*16 + li)*HID + kc*32 + lh*8];
      acc = __builtin_amdgcn_mfma_f32_16x16x32_bf16(a[kc], b, acc, 0, 0, 0);
    }
    int col = fc*16 + li;
    float bias = b1[col], w2v = w2[col];
    #pragma unroll
    for (int r = 0; r < 4; r++)
      psum[r] += ssp(acc[r] + bias) * w2v;
  }
  #pragma unroll
  for (int r = 0; r < 4; r++){
    psum[r] += __shfl_xor(psum[r], 1);
    psum[r] += __shfl_xor(psum[r], 2);
    psum[r] += __shfl_xor(psum[r], 4);
    psum[r] += __shfl_xor(psum[r], 8);
  }
  float b2v = b2[0];
  if (li == 0){
    #pragma unroll
    for (int r = 0; r < 4; r++) o_s[wv][lh*4 + r] = psum[r] + b2v;
  }
  float v = o_s[wv][li];
  int n2 = base + li;
  int seg = batch[n2];
  int segn = (li < 15) ? batch[n2 + 1] : -1;
  #pragma unroll
  for (int off = 1; off <= 8; off <<= 1){
    float vv = __shfl_up(v, off);
    int   ss = __shfl_up(seg, off);
    if (li >= off && ss == seg) v += vv;
  }
  if (l < 16 && (li == 15 || segn != seg)) atomicAdd(&out[seg], v);
}

extern "C" void kernel_launch(void* const* d_in, const int* in_sizes, int n_in,
                              void* d_out, int out_size, void* d_ws, size_t ws_size,
                              hipStream_t stream) {
  const float* h     = (const float*)d_in[0];
  const float* pos   = (const float*)d_in[1];
  const int*   ei    = (const int*)d_in[2];
  const int*   batch = (const int*)d_in[3];
  const float* mlp_w1 = (const float*)d_in[4];
  const float* mlp_b1 = (const float*)d_in[5];
  const float* mlp_w2 = (const float*)d_in[6];
  const float* mlp_b2 = (const float*)d_in[7];
  const float* cl1w  = (const float*)d_in[8];
  const float* cl2w  = (const float*)d_in[9];
  const float* cl2b  = (const float*)d_in[10];
  const float* linw  = (const float*)d_in[11];
  const float* linb  = (const float*)d_in[12];
  const float* o1w   = (const float*)d_in[13];
  const float* o1b   = (const float*)d_in[14];
  const float* o2w   = (const float*)d_in[15];
  const float* o2b   = (const float*)d_in[16];
  float* out = (float*)d_out;

  char* ws = (char*)d_ws;
  size_t off = 0;
  float* h_cur = (float*)(ws + off); off += (size_t)N_NODES*HID*4;
  u16*   aggb  = (u16*)  (ws + off); off += (size_t)N_NODES*NF*2;
  u16*   hxb   = (u16*)  (ws + off); off += (size_t)N_NODES*NF*2;
  u16*   tab   = (u16*)  (ws + off); off += (size_t)NL*TAB2*NF*2;
  u16*   w1T   = (u16*)  (ws + off); off += (size_t)NL*HID*NF*2;
  u16*   w2T   = (u16*)  (ws + off); off += (size_t)NL*NF*HID*2;
  u16*   lT    = (u16*)  (ws + off); off += (size_t)NL*HID*HID*2;
  u16*   o1wT  = (u16*)  (ws + off); off += (size_t)64*HID*2;
  unsigned* csr_pack = (unsigned*)(ws + off); off += (size_t)(N_EDGES + N_NODES + 32)*4;
  int* deg       = (int*)(ws + off); off += (size_t)N_NODES*4;
  int* row_start = (int*)(ws + off); off += (size_t)(N_NODES + 64)*4;
  int* cursor    = (int*)(ws + off); off += (size_t)N_NODES*4;
  int* bsum      = (int*)(ws + off); off += (size_t)64*4;

  hipMemsetAsync(out, 0, NSEG*sizeof(float), stream);
  hipMemsetAsync(deg, 0, N_NODES*sizeof(int), stream);
  hipMemsetAsync(cursor, 0, N_NODES*sizeof(int), stream);
  hipMemcpyAsync(h_cur, h, (size_t)N_NODES*HID*sizeof(float), hipMemcpyDeviceToDevice, stream);

  const int NSB = (N_NODES + 1023) / 1024; // 49
  k_hist<<<(N_EDGES/4 + 255)/256, 256, 0, stream>>>(ei + N_EDGES, deg);
  k_scan1<<<NSB, 1024, 0, stream>>>(deg, row_start, bsum);
  k_scan2<<<NSB, 1024, 0, stream>>>(bsum, deg, row_start);
  k_scatter<<<2048, 256, 0, stream>>>(ei, pos, row_start, cursor, csr_pack);
  k_pad<<<(N_NODES + 255)/256, 256, 0, stream>>>(deg, row_start, csr_pack);
  k_table<<<NL*TAB2, 128, 0, stream>>>(mlp_w1, mlp_b1, mlp_w2, mlp_b2, tab);
  k_wconv<<<NL*128, 128, 0, stream>>>(cl1w, w1T);
  k_wconv<<<NL*128, 128, 0, stream>>>(cl2w, w2T);
  k_wconv<<<NL*128, 128, 0, stream>>>(linw, lT);
  k_wconv64<<<64, 128, 0, stream>>>(o1w, o1wT);

  const int NBLK = (N_NODES + 63) / 64; // 782
  k_lin1m<<<NBLK, 256, 0, stream>>>(h_cur, w1T, hxb);
  for (int l = 0; l < NL; l++){
    k_edgeagg<<<N_NODES/4, 256, 0, stream>>>(row_start, csr_pack,
                                             tab + (size_t)l*TAB2*NF, hxb, aggb);
    const u16* w1n = (l + 1 < NL) ? (w1T + (size_t)(l+1)*HID*NF) : nullptr;
    k_nodefuse<<<NBLK, 256, 0, stream>>>(aggb, w2T + (size_t)l*NF*HID, cl2b + (size_t)l*HID,
                                         lT + (size_t)l*HID*HID, linb + (size_t)l*HID,
                                         h_cur, w1n, hxb);
  }
  k_out<<<NBLK, 256, 0, stream>>>(h_cur, o1wT, o1b, o2w, o2b, batch, out);
}

// Round 11
// 889.636 us; speedup vs baseline: 1.0924x; 1.0924x over previous
//
#include <hip/hip_runtime.h>
#include <math.h>

#define N_NODES 50000
#define N_EDGES 1600000
#define HID 128
#define NF 128
#define NG 50
#define NL 6
#define NSEG 64
#define TAB2 4096
#define CUTOFF 20.0f
#define LOG2F_ 0.6931471805599453f

typedef unsigned short u16;
typedef unsigned long long u64;
typedef __attribute__((ext_vector_type(8))) short short8;            // 8 bf16 MFMA A/B frag
typedef __attribute__((ext_vector_type(8))) unsigned short ushort8;  // 16B bf16 load
typedef __attribute__((ext_vector_type(4))) float f32x4;             // MFMA C/D frag

__device__ __forceinline__ float ssp(float x){
  float sp = fmaxf(x, 0.f) + log1pf(expf(-fabsf(x)));
  return sp - LOG2F_;
}
__device__ __forceinline__ float b2f(u16 u){
  unsigned v = ((unsigned)u) << 16; float f; __builtin_memcpy(&f, &v, 4); return f;
}
__device__ __forceinline__ u16 f2b(float f){
  unsigned u; __builtin_memcpy(&u, &f, 4);
  u += 0x7FFFu + ((u >> 16) & 1u);
  return (u16)(u >> 16);
}
// XOR-swizzled byte offset within a [16][128] bf16 tile (256B rows).
__device__ __forceinline__ int swz(int row, int colb){
  return row*256 + (colb ^ ((row & 15) << 4));
}

// ---------------- degree histogram (dst half only, int4) ----------------
__global__ __launch_bounds__(256) void k_hist(const int* __restrict__ ei_dst,
                                              int* __restrict__ deg){
  int e4 = blockIdx.x*blockDim.x + threadIdx.x;
  if (e4 < N_EDGES/4){
    int4 d = ((const int4*)ei_dst)[e4];
    atomicAdd(&deg[d.x], 1);
    atomicAdd(&deg[d.y], 1);
    atomicAdd(&deg[d.z], 1);
    atomicAdd(&deg[d.w], 1);
  }
}

// ---------------- parallel scan: phase 1 (block-local) ----------------
__global__ __launch_bounds__(1024) void k_scan1(const int* __restrict__ deg,
                                                int* __restrict__ row_start,
                                                int* __restrict__ bsum){
  int i = blockIdx.x*1024 + threadIdx.x;
  int lane = threadIdx.x & 63, w = threadIdx.x >> 6;
  int x = (i < N_NODES) ? deg[i] : 0;
  int v = x;
  #pragma unroll
  for (int off = 1; off < 64; off <<= 1){
    int t = __shfl_up(v, off);
    if (lane >= off) v += t;
  }
  __shared__ int ws[16];
  if (lane == 63) ws[w] = v;
  __syncthreads();
  if (w == 0 && lane < 16){
    int t = ws[lane];
    #pragma unroll
    for (int off = 1; off < 16; off <<= 1){
      int u = __shfl_up(t, off);
      if (lane >= off) t += u;
    }
    ws[lane] = t;
  }
  __syncthreads();
  int woff = (w > 0) ? ws[w-1] : 0;
  if (i < N_NODES) row_start[i] = woff + v - x;  // block-local exclusive
  if (threadIdx.x == 1023) bsum[blockIdx.x] = woff + v;
}

// ---------------- parallel scan: phase 2 (add block offsets) ----------------
__global__ __launch_bounds__(1024) void k_scan2(const int* __restrict__ bsum,
                                                int* __restrict__ row_start){
  __shared__ int boff_s;
  if (threadIdx.x < 64){
    int lane = threadIdx.x;
    int acc = 0;
    for (int b = lane; b < blockIdx.x; b += 64) acc += bsum[b];
    #pragma unroll
    for (int off = 32; off >= 1; off >>= 1) acc += __shfl_xor(acc, off);
    if (lane == 0) boff_s = acc;
  }
  __syncthreads();
  int i = blockIdx.x*1024 + threadIdx.x;
  if (i < N_NODES) row_start[i] += boff_s;
  if (i == 0) row_start[N_NODES] = N_EDGES;
}

// fused: distance + table index + pack + scatter (nt store)
__global__ __launch_bounds__(256) void k_scatter(const int* __restrict__ ei,
                                                 const float* __restrict__ pos,
                                                 const int* __restrict__ row_start,
                                                 int* __restrict__ cursor,
                                                 unsigned* __restrict__ csr_pack){
  const float INV_STEP = (TAB2 - 1) / CUTOFF;
  for (int e = blockIdx.x*blockDim.x + threadIdx.x; e < N_EDGES; e += gridDim.x*blockDim.x){
    int s = ei[e], t = ei[N_EDGES + e];
    float dx = pos[3*s]   - pos[3*t];
    float dy = pos[3*s+1] - pos[3*t+1];
    float dz = pos[3*s+2] - pos[3*t+2];
    float d = sqrtf(dx*dx + dy*dy + dz*dz);
    int j = (int)(d * INV_STEP + 0.5f);
    if (j > TAB2 - 1) j = TAB2 - 1;
    int slot = atomicAdd(&cursor[t], 1);
    int p = row_start[t] + slot;
    __builtin_nontemporal_store(((unsigned)j << 16) | (unsigned)s, &csr_pack[p]);
  }
}

// ---------------- weight convert: [in][out] fp32 -> [out][in] bf16 (128x128) ----------------
__global__ __launch_bounds__(128) void k_wconv(const float* __restrict__ w, u16* __restrict__ wT){
  int m = blockIdx.x >> 7, o = blockIdx.x & 127;
  int i = threadIdx.x;
  wT[((size_t)m*128 + o)*128 + i] = f2b(w[((size_t)m*128 + i)*128 + o]);
}
// [128][64] fp32 -> [64][128] bf16
__global__ __launch_bounds__(128) void k_wconv64(const float* __restrict__ w, u16* __restrict__ wT){
  int o = blockIdx.x;
  int i = threadIdx.x;
  wT[o*128 + i] = f2b(w[i*64 + o]);
}
// mlp_w1 [NL][NG=50][NF] fp32 -> [NL][NF][64] bf16, K zero-padded 50->64
__global__ __launch_bounds__(64) void k_wmlp1(const float* __restrict__ w, u16* __restrict__ wT){
  int l = blockIdx.x >> 7, o = blockIdx.x & 127;
  int k = threadIdx.x;
  wT[((size_t)l*128 + o)*64 + k] = (k < NG) ? f2b(w[((size_t)l*NG + k)*NF + o]) : (u16)0;
}

// ---------------- filter table via MFMA: W_l(d)*C(d), bf16 [l][j][f] ----------------
// per wave: 16 table rows. A = Gaussian features (16x64, zero-padded), GEMM1+ssp,
// GEMM2 + bias, * cosine cutoff per row, coalesced bf16 store.
__global__ __launch_bounds__(256) void k_tablem(const u16* __restrict__ w1mT,
                                                const float* __restrict__ b1,
                                                const u16* __restrict__ w2mT,
                                                const float* __restrict__ b2,
                                                u16* __restrict__ tab){
  int tid = threadIdx.x;
  int wv = tid >> 6, l = tid & 63;
  int lay = blockIdx.x >> 6;
  int j0 = ((blockIdx.x & 63) << 6) + wv*16;
  int li = l & 15, lh = l >> 4;
  __shared__ u16 tiles[4][16*128];
  char* tb = (char*)&tiles[wv][0];

  const float step2 = CUTOFF / (TAB2 - 1);
  const float gstep = CUTOFF / (NG - 1);
  const float coeff = -0.5f / (gstep*gstep);

  // A-frag: Gaussian smearing of row j0+li (K padded to 64)
  float d = (j0 + li) * step2;
  short8 a1[2];
  #pragma unroll
  for (int kc = 0; kc < 2; kc++){
    union { short8 v; u16 u[8]; } t;
    #pragma unroll
    for (int e = 0; e < 8; e++){
      int k = kc*32 + lh*8 + e;
      float u = d - k*gstep;
      float val = (k < NG) ? expf(coeff * u * u) : 0.f;
      t.u[e] = f2b(val);
    }
    a1[kc] = t.v;
  }
  // GEMM1 + bias + ssp -> swizzled tile
  #pragma unroll
  for (int fc = 0; fc < 8; fc++){
    f32x4 acc = {0.f,0.f,0.f,0.f};
    #pragma unroll
    for (int kc = 0; kc < 2; kc++){
      short8 b = *(const short8*)&w1mT[(size_t)(lay*128 + fc*16 + li)*64 + kc*32 + lh*8];
      acc = __builtin_amdgcn_mfma_f32_16x16x32_bf16(a1[kc], b, acc, 0, 0, 0);
    }
    float bias = b1[lay*NF + fc*16 + li];
    #pragma unroll
    for (int r = 0; r < 4; r++){
      float s = ssp(acc[r] + bias);
      *(u16*)(tb + swz(lh*4 + r, fc*32 + li*2)) = f2b(s);
    }
  }
  // A2 from tile
  short8 a2[4];
  #pragma unroll
  for (int kc = 0; kc < 4; kc++)
    a2[kc] = *(const short8*)(tb + swz(li, kc*64 + lh*16));
  // GEMM2 + bias, * C(row) -> tile
  #pragma unroll
  for (int fc = 0; fc < 8; fc++){
    f32x4 acc = {0.f,0.f,0.f,0.f};
    #pragma unroll
    for (int kc = 0; kc < 4; kc++){
      short8 b = *(const short8*)&w2mT[(size_t)(lay*128 + fc*16 + li)*128 + kc*32 + lh*8];
      acc = __builtin_amdgcn_mfma_f32_16x16x32_bf16(a2[kc], b, acc, 0, 0, 0);
    }
    float bias = b2[lay*NF + fc*16 + li];
    #pragma unroll
    for (int r = 0; r < 4; r++){
      float dr = (j0 + lh*4 + r) * step2;
      float C = 0.5f * (cosf(dr * (float)M_PI / CUTOFF) + 1.f);
      *(u16*)(tb + swz(lh*4 + r, fc*32 + li*2)) = f2b((acc[r] + bias) * C);
    }
  }
  // coalesced store
  #pragma unroll
  for (int g = 0; g < 4; g++){
    int row = g*4 + lh;
    short8 v = *(const short8*)(tb + swz(row, li*16));
    *(short8*)&tab[((size_t)lay*TAB2 + j0 + row)*NF + li*8] = v;
  }
}

// ---------------- layer-0 lin1: hxb = bf16(h @ w1) via MFMA ----------------
__global__ __launch_bounds__(256) void k_lin1m(const float* __restrict__ h,
                                               const u16* __restrict__ w1T,
                                               u16* __restrict__ hxb){
  int tid = threadIdx.x;
  int wv = tid >> 6, l = tid & 63;
  int n0 = blockIdx.x * 64 + wv * 16;
  if (n0 >= N_NODES) return;
  int li = l & 15, lh = l >> 4;
  __shared__ u16 tiles[4][16*128];
  char* tb = (char*)&tiles[wv][0];

  short8 a[4];
  #pragma unroll
  for (int kc = 0; kc < 4; kc++){
    const float* p = &h[(size_t)(n0 + li)*HID + kc*32 + lh*8];
    union { short8 v; u16 u[8]; } t;
    #pragma unroll
    for (int e = 0; e < 8; e++) t.u[e] = f2b(p[e]);
    a[kc] = t.v;
  }
  #pragma unroll
  for (int fc = 0; fc < 8; fc++){
    f32x4 acc = {0.f,0.f,0.f,0.f};
    #pragma unroll
    for (int kc = 0; kc < 4; kc++){
      short8 b = *(const short8*)&w1T[(size_t)(fc*16 + li)*HID + kc*32 + lh*8];
      acc = __builtin_amdgcn_mfma_f32_16x16x32_bf16(a[kc], b, acc, 0, 0, 0);
    }
    #pragma unroll
    for (int r = 0; r < 4; r++)
      *(u16*)(tb + swz(lh*4 + r, fc*32 + li*2)) = f2b(acc[r]);
  }
  #pragma unroll
  for (int g = 0; g < 4; g++){
    int row = g*4 + lh;
    short8 v = *(const short8*)(tb + swz(row, li*16));
    *(short8*)&hxb[(size_t)(n0 + row)*NF + li*8] = v;
  }
}

// ---------------- edge aggregation: 8 edges/wave-iter (2 per 16-lane group), dual acc ----------------
__global__ __launch_bounds__(256) void k_edgeagg(const int* __restrict__ row_start,
                                                 const unsigned* __restrict__ csr_pack,
                                                 const u16* __restrict__ tab_l,
                                                 const u16* __restrict__ hxb,
                                                 u16* __restrict__ aggb){
  int wave = threadIdx.x >> 6, lane = threadIdx.x & 63;
  int i = blockIdx.x * 4 + wave;
  int li = lane & 15, g = lane >> 4;
  int rs = row_start[i], re = row_start[i + 1];
  float acc0[8], acc1[8];
  #pragma unroll
  for (int r = 0; r < 8; r++){ acc0[r] = 0.f; acc1[r] = 0.f; }
  for (int p = rs + g; p < re; p += 8){
    int p1 = p + 4;
    bool ok1 = p1 < re;
    unsigned v0 = csr_pack[p];
    unsigned v1 = ok1 ? csr_pack[p1] : 0u;
    int s0 = (int)(v0 & 0xFFFFu), j0 = (int)(v0 >> 16);
    ushort8 hv0 = *(const ushort8*)&hxb[(size_t)s0 * NF + li*8];
    ushort8 wv0 = *(const ushort8*)&tab_l[(size_t)j0 * NF + li*8];
    if (ok1){
      int s1 = (int)(v1 & 0xFFFFu), j1 = (int)(v1 >> 16);
      ushort8 hv1 = *(const ushort8*)&hxb[(size_t)s1 * NF + li*8];
      ushort8 wv1 = *(const ushort8*)&tab_l[(size_t)j1 * NF + li*8];
      #pragma unroll
      for (int r = 0; r < 8; r++)
        acc1[r] += b2f(hv1[r]) * b2f(wv1[r]);
    }
    #pragma unroll
    for (int r = 0; r < 8; r++)
      acc0[r] += b2f(hv0[r]) * b2f(wv0[r]);
  }
  #pragma unroll
  for (int r = 0; r < 8; r++){
    float a = acc0[r] + acc1[r];
    a += __shfl_xor(a, 16);
    a += __shfl_xor(a, 32);
    acc0[r] = a;
  }
  if (g == 0){
    union { short8 v; u16 u[8]; } o;
    #pragma unroll
    for (int r = 0; r < 8; r++) o.u[r] = f2b(acc0[r]);
    *(short8*)&aggb[(size_t)i * NF + li*8] = o.v;
  }
}

// ---------------- fused node update via MFMA ----------------
__global__ __launch_bounds__(256) void k_nodefuse(const u16* __restrict__ aggb,
                                                  const u16* __restrict__ w2T, const float* __restrict__ b2b,
                                                  const u16* __restrict__ lT,  const float* __restrict__ linb,
                                                  float* __restrict__ h,
                                                  const u16* __restrict__ w1nT,
                                                  u16* __restrict__ hxb){
  int tid = threadIdx.x;
  int wv = tid >> 6, l = tid & 63;
  int n0 = blockIdx.x * 64 + wv * 16;
  if (n0 >= N_NODES) return;
  int li = l & 15, lh = l >> 4;
  __shared__ u16 tiles[4][16*128];
  char* tb = (char*)&tiles[wv][0];

  short8 a[4];
  #pragma unroll
  for (int kc = 0; kc < 4; kc++)
    a[kc] = *(const short8*)&aggb[(size_t)(n0 + li)*NF + kc*32 + lh*8];

  #pragma unroll
  for (int fc = 0; fc < 8; fc++){
    f32x4 acc = {0.f,0.f,0.f,0.f};
    #pragma unroll
    for (int kc = 0; kc < 4; kc++){
      short8 b = *(const short8*)&w2T[(size_t)(fc*16 + li)*NF + kc*32 + lh*8];
      acc = __builtin_amdgcn_mfma_f32_16x16x32_bf16(a[kc], b, acc, 0, 0, 0);
    }
    float bias = b2b[fc*16 + li];
    #pragma unroll
    for (int r = 0; r < 4; r++){
      float s = ssp(acc[r] + bias);
      *(u16*)(tb + swz(lh*4 + r, fc*32 + li*2)) = f2b(s);
    }
  }

  short8 a2[4];
  #pragma unroll
  for (int kc = 0; kc < 4; kc++)
    a2[kc] = *(const short8*)(tb + swz(li, kc*64 + lh*16));

  #pragma unroll
  for (int fc = 0; fc < 8; fc++){
    f32x4 acc = {0.f,0.f,0.f,0.f};
    #pragma unroll
    for (int kc = 0; kc < 4; kc++){
      short8 b = *(const short8*)&lT[(size_t)(fc*16 + li)*HID + kc*32 + lh*8];
      acc = __builtin_amdgcn_mfma_f32_16x16x32_bf16(a2[kc], b, acc, 0, 0, 0);
    }
    float bias = linb[fc*16 + li];
    #pragma unroll
    for (int r = 0; r < 4; r++){
      int i = lh*4 + r;
      size_t off = (size_t)(n0 + i)*HID + fc*16 + li;
      float hn = h[off] + acc[r] + bias;
      h[off] = hn;
      if (w1nT) *(u16*)(tb + swz(i, fc*32 + li*2)) = f2b(hn);
    }
  }
  if (!w1nT) return;

  short8 a3[4];
  #pragma unroll
  for (int kc = 0; kc < 4; kc++)
    a3[kc] = *(const short8*)(tb + swz(li, kc*64 + lh*16));
  #pragma unroll
  for (int fc = 0; fc < 8; fc++){
    f32x4 acc = {0.f,0.f,0.f,0.f};
    #pragma unroll
    for (int kc = 0; kc < 4; kc++){
      short8 b = *(const short8*)&w1nT[(size_t)(fc*16 + li)*HID + kc*32 + lh*8];
      acc = __builtin_amdgcn_mfma_f32_16x16x32_bf16(a3[kc], b, acc, 0, 0, 0);
    }
    #pragma unroll
    for (int r = 0; r < 4; r++)
      *(u16*)(tb + swz(lh*4 + r, fc*32 + li*2)) = f2b(acc[r]);
  }
  #pragma unroll
  for (int g = 0; g < 4; g++){
    int row = g*4 + lh;
    short8 v = *(const short8*)(tb + swz(row, li*16));
    *(short8*)&hxb[(size_t)(n0 + row)*NF + li*8] = v;
  }
}

// ---------------- readout via MFMA + wave segmented scan ----------------
__global__ __launch_bounds__(256) void k_out(const float* __restrict__ h,
                                             const u16* __restrict__ o1wT, const float* __restrict__ b1,
                                             const float* __restrict__ w2, const float* __restrict__ b2,
                                             const int* __restrict__ batch, float* __restrict__ out){
  int tid = threadIdx.x;
  int wv = tid >> 6, l = tid & 63;
  int base = blockIdx.x * 64 + wv * 16;
  if (base >= N_NODES) return;
  int li = l & 15, lh = l >> 4;
  __shared__ float o_s[4][16];

  short8 a[4];
  #pragma unroll
  for (int kc = 0; kc < 4; kc++){
    const float* p = &h[(size_t)(base + li)*HID + kc*32 + lh*8];
    union { short8 v; u16 u[8]; } t;
    #pragma unroll
    for (int e = 0; e < 8; e++) t.u[e] = f2b(p[e]);
    a[kc] = t.v;
  }
  float psum[4] = {0.f,0.f,0.f,0.f};
  #pragma unroll
  for (int fc = 0; fc < 4; fc++){
    f32x4 acc = {0.f,0.f,0.f,0.f};
    #pragma unroll
    for (int kc = 0; kc < 4; kc++){
      short8 b = *(const short8*)&o1wT[(size_t)(fc*16 + li)*HID + kc*32 + lh*8];
      acc = __builtin_amdgcn_mfma_f32_16x16x32_bf16(a[kc], b, acc, 0, 0, 0);
    }
    int col = fc*16 + li;
    float bias = b1[col], w2v = w2[col];
    #pragma unroll
    for (int r = 0; r < 4; r++)
      psum[r] += ssp(acc[r] + bias) * w2v;
  }
  #pragma unroll
  for (int r = 0; r < 4; r++){
    psum[r] += __shfl_xor(psum[r], 1);
    psum[r] += __shfl_xor(psum[r], 2);
    psum[r] += __shfl_xor(psum[r], 4);
    psum[r] += __shfl_xor(psum[r], 8);
  }
  float b2v = b2[0];
  if (li == 0){
    #pragma unroll
    for (int r = 0; r < 4; r++) o_s[wv][lh*4 + r] = psum[r] + b2v;
  }
  float v = o_s[wv][li];
  int n2 = base + li;
  int seg = batch[n2];
  int segn = (li < 15) ? batch[n2 + 1] : -1;
  #pragma unroll
  for (int off = 1; off <= 8; off <<= 1){
    float vv = __shfl_up(v, off);
    int   ss = __shfl_up(seg, off);
    if (li >= off && ss == seg) v += vv;
  }
  if (l < 16 && (li == 15 || segn != seg)) atomicAdd(&out[seg], v);
}

extern "C" void kernel_launch(void* const* d_in, const int* in_sizes, int n_in,
                              void* d_out, int out_size, void* d_ws, size_t ws_size,
                              hipStream_t stream) {
  const float* h     = (const float*)d_in[0];
  const float* pos   = (const float*)d_in[1];
  const int*   ei    = (const int*)d_in[2];
  const int*   batch = (const int*)d_in[3];
  const float* mlp_w1 = (const float*)d_in[4];
  const float* mlp_b1 = (const float*)d_in[5];
  const float* mlp_w2 = (const float*)d_in[6];
  const float* mlp_b2 = (const float*)d_in[7];
  const float* cl1w  = (const float*)d_in[8];
  const float* cl2w  = (const float*)d_in[9];
  const float* cl2b  = (const float*)d_in[10];
  const float* linw  = (const float*)d_in[11];
  const float* linb  = (const float*)d_in[12];
  const float* o1w   = (const float*)d_in[13];
  const float* o1b   = (const float*)d_in[14];
  const float* o2w   = (const float*)d_in[15];
  const float* o2b   = (const float*)d_in[16];
  float* out = (float*)d_out;

  char* ws = (char*)d_ws;
  size_t off = 0;
  float* h_cur = (float*)(ws + off); off += (size_t)N_NODES*HID*4;
  u16*   aggb  = (u16*)  (ws + off); off += (size_t)N_NODES*NF*2;
  u16*   hxb   = (u16*)  (ws + off); off += (size_t)N_NODES*NF*2;
  u16*   tab   = (u16*)  (ws + off); off += (size_t)NL*TAB2*NF*2;
  u16*   w1T   = (u16*)  (ws + off); off += (size_t)NL*HID*NF*2;
  u16*   w2T   = (u16*)  (ws + off); off += (size_t)NL*NF*HID*2;
  u16*   lT    = (u16*)  (ws + off); off += (size_t)NL*HID*HID*2;
  u16*   o1wT  = (u16*)  (ws + off); off += (size_t)64*HID*2;
  u16*   w1mT  = (u16*)  (ws + off); off += (size_t)NL*NF*64*2;
  u16*   w2mT  = (u16*)  (ws + off); off += (size_t)NL*NF*NF*2;
  unsigned* csr_pack = (unsigned*)(ws + off); off += (size_t)(N_EDGES + 16)*4;
  int* deg       = (int*)(ws + off); off += (size_t)N_NODES*4;
  int* row_start = (int*)(ws + off); off += (size_t)(N_NODES + 64)*4;
  int* cursor    = (int*)(ws + off); off += (size_t)N_NODES*4;
  int* bsum      = (int*)(ws + off); off += (size_t)64*4;

  hipMemsetAsync(out, 0, NSEG*sizeof(float), stream);
  hipMemsetAsync(deg, 0, N_NODES*sizeof(int), stream);
  hipMemsetAsync(cursor, 0, N_NODES*sizeof(int), stream);
  hipMemcpyAsync(h_cur, h, (size_t)N_NODES*HID*sizeof(float), hipMemcpyDeviceToDevice, stream);

  const int NSB = (N_NODES + 1023) / 1024; // 49
  k_hist<<<(N_EDGES/4 + 255)/256, 256, 0, stream>>>(ei + N_EDGES, deg);
  k_scan1<<<NSB, 1024, 0, stream>>>(deg, row_start, bsum);
  k_scan2<<<NSB, 1024, 0, stream>>>(bsum, row_start);
  k_scatter<<<2048, 256, 0, stream>>>(ei, pos, row_start, cursor, csr_pack);
  k_wmlp1<<<NL*128, 64, 0, stream>>>(mlp_w1, w1mT);
  k_wconv<<<NL*128, 128, 0, stream>>>(mlp_w2, w2mT);
  k_tablem<<<NL*64, 256, 0, stream>>>(w1mT, mlp_b1, w2mT, mlp_b2, tab);
  k_wconv<<<NL*128, 128, 0, stream>>>(cl1w, w1T);
  k_wconv<<<NL*128, 128, 0, stream>>>(cl2w, w2T);
  k_wconv<<<NL*128, 128, 0, stream>>>(linw, lT);
  k_wconv64<<<64, 128, 0, stream>>>(o1w, o1wT);

  const int NBLK = (N_NODES + 63) / 64; // 782
  k_lin1m<<<NBLK, 256, 0, stream>>>(h_cur, w1T, hxb);
  for (int l = 0; l < NL; l++){
    k_edgeagg<<<N_NODES/4, 256, 0, stream>>>(row_start, csr_pack,
                                             tab + (size_t)l*TAB2*NF, hxb, aggb);
    const u16* w1n = (l + 1 < NL) ? (w1T + (size_t)(l+1)*HID*NF) : nullptr;
    k_nodefuse<<<NBLK, 256, 0, stream>>>(aggb, w2T + (size_t)l*NF*HID, cl2b + (size_t)l*HID,
                                         lT + (size_t)l*HID*HID, linb + (size_t)l*HID,
                                         h_cur, w1n, hxb);
  }
  k_out<<<NBLK, 256, 0, stream>>>(h_cur, o1wT, o1b, o2w, o2b, batch, out);
}